// Round 4
// baseline (100.486 us; speedup 1.0000x reference)
//
#include <hip/hip_runtime.h>

// Butterfly (untied, increasing stride): BATCH=16384, N=1024, M=10, NSTACK=1.
// out = butterfly_mult(twiddle, x) + bias, all float32.
//
// Layout: pos = e_hi*256 + lane*4 + e_lo  (e_hi, e_lo in 0..3).
//   - stages 0..1: in-register pairs over e_lo bits.
//   - stages 2..7: cross-lane __shfl_xor over lane bits.
//   - stages 8..9: in-register pairs over e_hi bits.
//
// v4: twiddle is pre-repacked into d_ws as tws[stage][k][lane] (float4) by a
//     tiny kernel, so ALL twiddle reads in the main kernel are lane-contiguous
//     coalesced float4 (the raw layout produced 32-64 cache-line gathers per
//     instruction, which saturated the L1/TA pipe -> perf was occupancy-
//     independent). RPW=4 amortizes twiddle reads over 4 rows.

#define BATCH 16384
#define NCOL 1024
#define RPW 4
#define TWS_BYTES (10 * 8 * 64 * 16)  // 81920

// ---------------- repack kernel: blockIdx.x = stage, threadIdx.x = lane ----
__global__ __launch_bounds__(64) void repack_tw(
    const float* __restrict__ tw, float4* __restrict__ ws)
{
    const int s = blockIdx.x;
    const int lane = threadIdx.x;
    const float4* raw4 = reinterpret_cast<const float4*>(tw + s * 2048);
    const float2* raw2 = reinterpret_cast<const float2*>(tw + s * 2048);

    #pragma unroll
    for (int k = 0; k < 8; ++k) {
        float4 val;
        if (s < 2) {
            const int eh = k >> 1, j = k & 1;
            val = raw4[eh * 128 + lane * 2 + j];
        } else if (s < 8) {
            const int b = s - 2, m = 1 << b;
            const int i = (lane >> b) & 1;
            const int lp = ((lane >> (b + 1)) << b) | (lane & (m - 1));
            const int eh = k >> 1, ep = k & 1;
            float2 a = raw2[(eh * 128 + lp * 4 + 2 * ep) * 2 + i];
            float2 c = raw2[(eh * 128 + lp * 4 + 2 * ep + 1) * 2 + i];
            val = make_float4(a.x, a.y, c.x, c.y);
        } else {
            const int g = k >> 2, el = k & 3;
            val = raw4[g * 256 + lane * 4 + el];
        }
        ws[(s * 8 + k) * 64 + lane] = val;
    }
}

// ---------------- main kernel (repacked twiddle) ---------------------------
__global__ __launch_bounds__(256, 4) void butterfly_kernel(
    const float* __restrict__ x,
    const float4* __restrict__ tws,
    const float* __restrict__ bias,
    float* __restrict__ out)
{
    const int lane = threadIdx.x & 63;
    const int wave_in_block = threadIdx.x >> 6;
    const int gwave = blockIdx.x * 4 + wave_in_block;
    const int row0 = gwave * RPW;

    float v[RPW][4][4];

    const float4* x4 = reinterpret_cast<const float4*>(x);
    #pragma unroll
    for (int q = 0; q < RPW; ++q) {
        #pragma unroll
        for (int eh = 0; eh < 4; ++eh) {
            float4 t = x4[(row0 + q) * 256 + eh * 64 + lane];
            v[q][eh][0] = t.x; v[q][eh][1] = t.y;
            v[q][eh][2] = t.z; v[q][eh][3] = t.w;
        }
    }

    // ---- stage 0: pairs (e_lo 0,1),(2,3)
    #pragma unroll
    for (int k = 0; k < 8; ++k) {
        const float4 T = tws[(0 * 8 + k) * 64 + lane];
        const int eh = k >> 1, j = k & 1;
        #pragma unroll
        for (int q = 0; q < RPW; ++q) {
            const float a = v[q][eh][2 * j];
            const float b = v[q][eh][2 * j + 1];
            v[q][eh][2 * j]     = T.x * a + T.y * b;
            v[q][eh][2 * j + 1] = T.z * a + T.w * b;
        }
    }

    // ---- stage 1: pairs (e_lo 0,2),(1,3)
    #pragma unroll
    for (int k = 0; k < 8; ++k) {
        const float4 T = tws[(1 * 8 + k) * 64 + lane];
        const int eh = k >> 1, j = k & 1;
        #pragma unroll
        for (int q = 0; q < RPW; ++q) {
            const float a = v[q][eh][j];
            const float b = v[q][eh][j + 2];
            v[q][eh][j]     = T.x * a + T.y * b;
            v[q][eh][j + 2] = T.z * a + T.w * b;
        }
    }

    // ---- stages 2..7: partner lane = lane ^ (1 << (s-2))
    #pragma unroll
    for (int s = 2; s < 8; ++s) {
        const int b = s - 2;
        const int m = 1 << b;
        const int i = (lane >> b) & 1;   // bit s of pos
        float4 T[8];
        #pragma unroll
        for (int k = 0; k < 8; ++k) T[k] = tws[(s * 8 + k) * 64 + lane];
        #pragma unroll
        for (int q = 0; q < RPW; ++q) {
            #pragma unroll
            for (int k = 0; k < 8; ++k) {
                const int eh = k >> 1, ep = k & 1;
                {
                    const float own = v[q][eh][2 * ep];
                    const float p = __shfl_xor(own, m, 64);
                    const float x0 = i ? p : own;
                    const float x1 = i ? own : p;
                    v[q][eh][2 * ep] = T[k].x * x0 + T[k].y * x1;
                }
                {
                    const float own = v[q][eh][2 * ep + 1];
                    const float p = __shfl_xor(own, m, 64);
                    const float x0 = i ? p : own;
                    const float x1 = i ? own : p;
                    v[q][eh][2 * ep + 1] = T[k].z * x0 + T[k].w * x1;
                }
            }
        }
    }

    // ---- stage 8: pairs (e_hi 0,1),(2,3)
    #pragma unroll
    for (int k = 0; k < 8; ++k) {
        const float4 T = tws[(8 * 8 + k) * 64 + lane];
        const int g = k >> 2, el = k & 3;
        #pragma unroll
        for (int q = 0; q < RPW; ++q) {
            const float a = v[q][2 * g][el];
            const float b = v[q][2 * g + 1][el];
            v[q][2 * g][el]     = T.x * a + T.y * b;
            v[q][2 * g + 1][el] = T.z * a + T.w * b;
        }
    }

    // ---- stage 9: pairs (e_hi 0,2),(1,3)
    #pragma unroll
    for (int k = 0; k < 8; ++k) {
        const float4 T = tws[(9 * 8 + k) * 64 + lane];
        const int h = k >> 2, el = k & 3;
        #pragma unroll
        for (int q = 0; q < RPW; ++q) {
            const float a = v[q][h][el];
            const float b = v[q][h + 2][el];
            v[q][h][el]     = T.x * a + T.y * b;
            v[q][h + 2][el] = T.z * a + T.w * b;
        }
    }

    // ---- bias + store
    float4* o4 = reinterpret_cast<float4*>(out);
    const float4* b4 = reinterpret_cast<const float4*>(bias);
    #pragma unroll
    for (int eh = 0; eh < 4; ++eh) {
        const float4 bb = b4[eh * 64 + lane];
        #pragma unroll
        for (int q = 0; q < RPW; ++q) {
            float4 t;
            t.x = v[q][eh][0] + bb.x;
            t.y = v[q][eh][1] + bb.y;
            t.z = v[q][eh][2] + bb.z;
            t.w = v[q][eh][3] + bb.w;
            o4[(row0 + q) * 256 + eh * 64 + lane] = t;
        }
    }
}

// ---------------- fallback (raw twiddle, RPW=2) ----------------------------
__global__ __launch_bounds__(256, 4) void butterfly_fallback(
    const float* __restrict__ x,
    const float* __restrict__ tw,
    const float* __restrict__ bias,
    float* __restrict__ out)
{
    const int lane = threadIdx.x & 63;
    const int wave_in_block = threadIdx.x >> 6;
    const int gwave = blockIdx.x * 4 + wave_in_block;
    const int row0 = gwave * 2;

    float v[2][4][4];
    const float4* x4 = reinterpret_cast<const float4*>(x);
    #pragma unroll
    for (int q = 0; q < 2; ++q)
        #pragma unroll
        for (int eh = 0; eh < 4; ++eh) {
            float4 t = x4[(row0 + q) * 256 + eh * 64 + lane];
            v[q][eh][0] = t.x; v[q][eh][1] = t.y;
            v[q][eh][2] = t.z; v[q][eh][3] = t.w;
        }

    #pragma unroll
    for (int s = 0; s < 2; ++s) {
        const float4* t4 = reinterpret_cast<const float4*>(tw + s * 2048);
        #pragma unroll
        for (int eh = 0; eh < 4; ++eh)
            #pragma unroll
            for (int j = 0; j < 2; ++j) {
                const float4 T = t4[eh * 128 + lane * 2 + j];
                #pragma unroll
                for (int q = 0; q < 2; ++q) {
                    const int a0 = (s == 0) ? 2 * j : j;
                    const int a1 = (s == 0) ? 2 * j + 1 : j + 2;
                    const float a = v[q][eh][a0];
                    const float b = v[q][eh][a1];
                    v[q][eh][a0] = T.x * a + T.y * b;
                    v[q][eh][a1] = T.z * a + T.w * b;
                }
            }
    }
    #pragma unroll
    for (int s = 2; s < 8; ++s) {
        const int b = s - 2, m = 1 << b;
        const int i = (lane >> b) & 1;
        const int lp = ((lane >> (b + 1)) << b) | (lane & (m - 1));
        const float2* t2 = reinterpret_cast<const float2*>(tw + s * 2048);
        float2 T[4][4];
        #pragma unroll
        for (int eh = 0; eh < 4; ++eh)
            #pragma unroll
            for (int el = 0; el < 4; ++el)
                T[eh][el] = t2[(eh * 128 + lp * 4 + el) * 2 + i];
        #pragma unroll
        for (int q = 0; q < 2; ++q)
            #pragma unroll
            for (int eh = 0; eh < 4; ++eh)
                #pragma unroll
                for (int el = 0; el < 4; ++el) {
                    const float own = v[q][eh][el];
                    const float p = __shfl_xor(own, m, 64);
                    const float x0 = i ? p : own;
                    const float x1 = i ? own : p;
                    v[q][eh][el] = T[eh][el].x * x0 + T[eh][el].y * x1;
                }
    }
    #pragma unroll
    for (int s = 8; s < 10; ++s) {
        const float4* t4 = reinterpret_cast<const float4*>(tw + s * 2048);
        #pragma unroll
        for (int g = 0; g < 2; ++g)
            #pragma unroll
            for (int el = 0; el < 4; ++el) {
                const float4 T = t4[g * 256 + lane * 4 + el];
                #pragma unroll
                for (int q = 0; q < 2; ++q) {
                    const int a0 = (s == 8) ? 2 * g : g;
                    const int a1 = (s == 8) ? 2 * g + 1 : g + 2;
                    const float a = v[q][a0][el];
                    const float b = v[q][a1][el];
                    v[q][a0][el] = T.x * a + T.y * b;
                    v[q][a1][el] = T.z * a + T.w * b;
                }
            }
    }
    float4* o4 = reinterpret_cast<float4*>(out);
    const float4* b4 = reinterpret_cast<const float4*>(bias);
    #pragma unroll
    for (int eh = 0; eh < 4; ++eh) {
        const float4 bb = b4[eh * 64 + lane];
        #pragma unroll
        for (int q = 0; q < 2; ++q) {
            float4 t;
            t.x = v[q][eh][0] + bb.x;
            t.y = v[q][eh][1] + bb.y;
            t.z = v[q][eh][2] + bb.z;
            t.w = v[q][eh][3] + bb.w;
            o4[(row0 + q) * 256 + eh * 64 + lane] = t;
        }
    }
}

extern "C" void kernel_launch(void* const* d_in, const int* in_sizes, int n_in,
                              void* d_out, int out_size, void* d_ws, size_t ws_size,
                              hipStream_t stream) {
    const float* x    = (const float*)d_in[0];  // (16384, 1024)
    const float* tw   = (const float*)d_in[1];  // (1, 10, 512, 2, 2)
    const float* bias = (const float*)d_in[2];  // (1024,)
    float* out = (float*)d_out;

    if (ws_size >= TWS_BYTES) {
        float4* tws = (float4*)d_ws;
        repack_tw<<<10, 64, 0, stream>>>(tw, tws);
        const int blocks = (BATCH / RPW) / 4;   // 1024
        butterfly_kernel<<<blocks, 256, 0, stream>>>(x, tws, bias, out);
    } else {
        const int blocks = (BATCH / 2) / 4;     // 2048
        butterfly_fallback<<<blocks, 256, 0, stream>>>(x, tw, bias, out);
    }
}

// Round 5
// 42.801 us; speedup vs baseline: 2.3477x; 2.3477x over previous
//
#include <hip/hip_runtime.h>

// Butterfly (untied, increasing stride): BATCH=16384, N=1024, M=10, NSTACK=1.
// out = butterfly_mult(twiddle, x) + bias, all float32.
//
// Layout: pos = e_hi*256 + lane*4 + e_lo  (e_hi, e_lo in 0..3).
//   - stages 0..1: in-register pairs over e_lo bits.
//   - stages 2..7: cross-lane __shfl_xor over lane bits.
//   - stages 8..9: in-register pairs over e_hi bits.
//
// v5: repacked twiddle (tws[stage][k][lane] float4, coalesced reads) kept
//     from v4, but RPW back to 2: v4's RPW=4 + launch_bounds(256,4) forced
//     VGPR<=128 while the kernel needs ~140 -> scratch spill (WRITE_SIZE
//     64MiB->249MB, dur 100us). RPW=2 measured 64 VGPR natural in round 3;
//     with twiddle staging it stays well under the 128 cliff -> no spill,
//     4 waves/SIMD.

#define BATCH 16384
#define NCOL 1024
#define RPW 2
#define TWS_BYTES (10 * 8 * 64 * 16)  // 81920

// ---------------- repack kernel: blockIdx.x = stage, threadIdx.x = lane ----
__global__ __launch_bounds__(64) void repack_tw(
    const float* __restrict__ tw, float4* __restrict__ ws)
{
    const int s = blockIdx.x;
    const int lane = threadIdx.x;
    const float4* raw4 = reinterpret_cast<const float4*>(tw + s * 2048);
    const float2* raw2 = reinterpret_cast<const float2*>(tw + s * 2048);

    #pragma unroll
    for (int k = 0; k < 8; ++k) {
        float4 val;
        if (s < 2) {
            const int eh = k >> 1, j = k & 1;
            val = raw4[eh * 128 + lane * 2 + j];
        } else if (s < 8) {
            const int b = s - 2, m = 1 << b;
            const int i = (lane >> b) & 1;
            const int lp = ((lane >> (b + 1)) << b) | (lane & (m - 1));
            const int eh = k >> 1, ep = k & 1;
            float2 a = raw2[(eh * 128 + lp * 4 + 2 * ep) * 2 + i];
            float2 c = raw2[(eh * 128 + lp * 4 + 2 * ep + 1) * 2 + i];
            val = make_float4(a.x, a.y, c.x, c.y);
        } else {
            const int g = k >> 2, el = k & 3;
            val = raw4[g * 256 + lane * 4 + el];
        }
        ws[(s * 8 + k) * 64 + lane] = val;
    }
}

// ---------------- main kernel (repacked twiddle) ---------------------------
__global__ __launch_bounds__(256, 4) void butterfly_kernel(
    const float* __restrict__ x,
    const float4* __restrict__ tws,
    const float* __restrict__ bias,
    float* __restrict__ out)
{
    const int lane = threadIdx.x & 63;
    const int wave_in_block = threadIdx.x >> 6;
    const int gwave = blockIdx.x * 4 + wave_in_block;
    const int row0 = gwave * RPW;

    float v[RPW][4][4];

    const float4* x4 = reinterpret_cast<const float4*>(x);
    #pragma unroll
    for (int q = 0; q < RPW; ++q) {
        #pragma unroll
        for (int eh = 0; eh < 4; ++eh) {
            float4 t = x4[(row0 + q) * 256 + eh * 64 + lane];
            v[q][eh][0] = t.x; v[q][eh][1] = t.y;
            v[q][eh][2] = t.z; v[q][eh][3] = t.w;
        }
    }

    // ---- stage 0: pairs (e_lo 0,1),(2,3)
    #pragma unroll
    for (int k = 0; k < 8; ++k) {
        const float4 T = tws[(0 * 8 + k) * 64 + lane];
        const int eh = k >> 1, j = k & 1;
        #pragma unroll
        for (int q = 0; q < RPW; ++q) {
            const float a = v[q][eh][2 * j];
            const float b = v[q][eh][2 * j + 1];
            v[q][eh][2 * j]     = T.x * a + T.y * b;
            v[q][eh][2 * j + 1] = T.z * a + T.w * b;
        }
    }

    // ---- stage 1: pairs (e_lo 0,2),(1,3)
    #pragma unroll
    for (int k = 0; k < 8; ++k) {
        const float4 T = tws[(1 * 8 + k) * 64 + lane];
        const int eh = k >> 1, j = k & 1;
        #pragma unroll
        for (int q = 0; q < RPW; ++q) {
            const float a = v[q][eh][j];
            const float b = v[q][eh][j + 2];
            v[q][eh][j]     = T.x * a + T.y * b;
            v[q][eh][j + 2] = T.z * a + T.w * b;
        }
    }

    // ---- stages 2..7: partner lane = lane ^ (1 << (s-2))
    #pragma unroll
    for (int s = 2; s < 8; ++s) {
        const int b = s - 2;
        const int m = 1 << b;
        const int i = (lane >> b) & 1;   // bit s of pos
        float4 T[8];
        #pragma unroll
        for (int k = 0; k < 8; ++k) T[k] = tws[(s * 8 + k) * 64 + lane];
        #pragma unroll
        for (int q = 0; q < RPW; ++q) {
            #pragma unroll
            for (int k = 0; k < 8; ++k) {
                const int eh = k >> 1, ep = k & 1;
                {
                    const float own = v[q][eh][2 * ep];
                    const float p = __shfl_xor(own, m, 64);
                    const float x0 = i ? p : own;
                    const float x1 = i ? own : p;
                    v[q][eh][2 * ep] = T[k].x * x0 + T[k].y * x1;
                }
                {
                    const float own = v[q][eh][2 * ep + 1];
                    const float p = __shfl_xor(own, m, 64);
                    const float x0 = i ? p : own;
                    const float x1 = i ? own : p;
                    v[q][eh][2 * ep + 1] = T[k].z * x0 + T[k].w * x1;
                }
            }
        }
    }

    // ---- stage 8: pairs (e_hi 0,1),(2,3)
    #pragma unroll
    for (int k = 0; k < 8; ++k) {
        const float4 T = tws[(8 * 8 + k) * 64 + lane];
        const int g = k >> 2, el = k & 3;
        #pragma unroll
        for (int q = 0; q < RPW; ++q) {
            const float a = v[q][2 * g][el];
            const float b = v[q][2 * g + 1][el];
            v[q][2 * g][el]     = T.x * a + T.y * b;
            v[q][2 * g + 1][el] = T.z * a + T.w * b;
        }
    }

    // ---- stage 9: pairs (e_hi 0,2),(1,3)
    #pragma unroll
    for (int k = 0; k < 8; ++k) {
        const float4 T = tws[(9 * 8 + k) * 64 + lane];
        const int h = k >> 2, el = k & 3;
        #pragma unroll
        for (int q = 0; q < RPW; ++q) {
            const float a = v[q][h][el];
            const float b = v[q][h + 2][el];
            v[q][h][el]     = T.x * a + T.y * b;
            v[q][h + 2][el] = T.z * a + T.w * b;
        }
    }

    // ---- bias + store
    float4* o4 = reinterpret_cast<float4*>(out);
    const float4* b4 = reinterpret_cast<const float4*>(bias);
    #pragma unroll
    for (int eh = 0; eh < 4; ++eh) {
        const float4 bb = b4[eh * 64 + lane];
        #pragma unroll
        for (int q = 0; q < RPW; ++q) {
            float4 t;
            t.x = v[q][eh][0] + bb.x;
            t.y = v[q][eh][1] + bb.y;
            t.z = v[q][eh][2] + bb.z;
            t.w = v[q][eh][3] + bb.w;
            o4[(row0 + q) * 256 + eh * 64 + lane] = t;
        }
    }
}

// ---------------- fallback (raw twiddle, RPW=2) ----------------------------
__global__ __launch_bounds__(256, 4) void butterfly_fallback(
    const float* __restrict__ x,
    const float* __restrict__ tw,
    const float* __restrict__ bias,
    float* __restrict__ out)
{
    const int lane = threadIdx.x & 63;
    const int wave_in_block = threadIdx.x >> 6;
    const int gwave = blockIdx.x * 4 + wave_in_block;
    const int row0 = gwave * 2;

    float v[2][4][4];
    const float4* x4 = reinterpret_cast<const float4*>(x);
    #pragma unroll
    for (int q = 0; q < 2; ++q)
        #pragma unroll
        for (int eh = 0; eh < 4; ++eh) {
            float4 t = x4[(row0 + q) * 256 + eh * 64 + lane];
            v[q][eh][0] = t.x; v[q][eh][1] = t.y;
            v[q][eh][2] = t.z; v[q][eh][3] = t.w;
        }

    #pragma unroll
    for (int s = 0; s < 2; ++s) {
        const float4* t4 = reinterpret_cast<const float4*>(tw + s * 2048);
        #pragma unroll
        for (int eh = 0; eh < 4; ++eh)
            #pragma unroll
            for (int j = 0; j < 2; ++j) {
                const float4 T = t4[eh * 128 + lane * 2 + j];
                #pragma unroll
                for (int q = 0; q < 2; ++q) {
                    const int a0 = (s == 0) ? 2 * j : j;
                    const int a1 = (s == 0) ? 2 * j + 1 : j + 2;
                    const float a = v[q][eh][a0];
                    const float b = v[q][eh][a1];
                    v[q][eh][a0] = T.x * a + T.y * b;
                    v[q][eh][a1] = T.z * a + T.w * b;
                }
            }
    }
    #pragma unroll
    for (int s = 2; s < 8; ++s) {
        const int b = s - 2, m = 1 << b;
        const int i = (lane >> b) & 1;
        const int lp = ((lane >> (b + 1)) << b) | (lane & (m - 1));
        const float2* t2 = reinterpret_cast<const float2*>(tw + s * 2048);
        float2 T[4][4];
        #pragma unroll
        for (int eh = 0; eh < 4; ++eh)
            #pragma unroll
            for (int el = 0; el < 4; ++el)
                T[eh][el] = t2[(eh * 128 + lp * 4 + el) * 2 + i];
        #pragma unroll
        for (int q = 0; q < 2; ++q)
            #pragma unroll
            for (int eh = 0; eh < 4; ++eh)
                #pragma unroll
                for (int el = 0; el < 4; ++el) {
                    const float own = v[q][eh][el];
                    const float p = __shfl_xor(own, m, 64);
                    const float x0 = i ? p : own;
                    const float x1 = i ? own : p;
                    v[q][eh][el] = T[eh][el].x * x0 + T[eh][el].y * x1;
                }
    }
    #pragma unroll
    for (int s = 8; s < 10; ++s) {
        const float4* t4 = reinterpret_cast<const float4*>(tw + s * 2048);
        #pragma unroll
        for (int g = 0; g < 2; ++g)
            #pragma unroll
            for (int el = 0; el < 4; ++el) {
                const float4 T = t4[g * 256 + lane * 4 + el];
                #pragma unroll
                for (int q = 0; q < 2; ++q) {
                    const int a0 = (s == 8) ? 2 * g : g;
                    const int a1 = (s == 8) ? 2 * g + 1 : g + 2;
                    const float a = v[q][a0][el];
                    const float b = v[q][a1][el];
                    v[q][a0][el] = T.x * a + T.y * b;
                    v[q][a1][el] = T.z * a + T.w * b;
                }
            }
    }
    float4* o4 = reinterpret_cast<float4*>(out);
    const float4* b4 = reinterpret_cast<const float4*>(bias);
    #pragma unroll
    for (int eh = 0; eh < 4; ++eh) {
        const float4 bb = b4[eh * 64 + lane];
        #pragma unroll
        for (int q = 0; q < 2; ++q) {
            float4 t;
            t.x = v[q][eh][0] + bb.x;
            t.y = v[q][eh][1] + bb.y;
            t.z = v[q][eh][2] + bb.z;
            t.w = v[q][eh][3] + bb.w;
            o4[(row0 + q) * 256 + eh * 64 + lane] = t;
        }
    }
}

extern "C" void kernel_launch(void* const* d_in, const int* in_sizes, int n_in,
                              void* d_out, int out_size, void* d_ws, size_t ws_size,
                              hipStream_t stream) {
    const float* x    = (const float*)d_in[0];  // (16384, 1024)
    const float* tw   = (const float*)d_in[1];  // (1, 10, 512, 2, 2)
    const float* bias = (const float*)d_in[2];  // (1024,)
    float* out = (float*)d_out;

    if (ws_size >= TWS_BYTES) {
        float4* tws = (float4*)d_ws;
        repack_tw<<<10, 64, 0, stream>>>(tw, tws);
        const int blocks = (BATCH / RPW) / 4;   // 2048
        butterfly_kernel<<<blocks, 256, 0, stream>>>(x, tws, bias, out);
    } else {
        const int blocks = (BATCH / 2) / 4;     // 2048
        butterfly_fallback<<<blocks, 256, 0, stream>>>(x, tw, bias, out);
    }
}